// Round 4
// baseline (171.306 us; speedup 1.0000x reference)
//
#include <hip/hip_runtime.h>

#define B_ROWS 16384
#define S_ROWS 12800
#define DIM    128

static constexpr float SCL = 20.609929155556617f;  // log2(e) / 0.07

typedef __attribute__((ext_vector_type(8))) short short8;
typedef __attribute__((ext_vector_type(4))) float f32x4;

// f32 -> bf16 round-to-nearest-even
__device__ __forceinline__ unsigned short f2bf(float f) {
  unsigned int u = __float_as_uint(f);
  unsigned int r = (u + 0x7FFFu + ((u >> 16) & 1u)) >> 16;
  return (unsigned short)r;
}

// Sortable packing: larger float -> larger key; ties -> smaller col wins (matches jnp.argmax).
__device__ __forceinline__ unsigned long long packMax(float v, int col) {
  unsigned int b = __float_as_uint(v);
  unsigned int key = (b & 0x80000000u) ? ~b : (b | 0x80000000u);
  return ((unsigned long long)key << 32) | (unsigned long long)(0xFFFFFFFFu - (unsigned int)col);
}

// async global->LDS, 16B per lane, wave-uniform LDS base (HW adds lane*16)
__device__ __forceinline__ void gld16(const unsigned short* g, unsigned short* l) {
  __builtin_amdgcn_global_load_lds(
      (const __attribute__((address_space(1))) unsigned int*)g,
      (__attribute__((address_space(3))) unsigned int*)l,
      16, 0, 0);
}

#define WAIT_LGKM0 asm volatile("s_waitcnt lgkmcnt(0)" ::: "memory")
#define WAIT_VM8   asm volatile("s_waitcnt vmcnt(8)" ::: "memory")
#define WAIT_VM0   asm volatile("s_waitcnt vmcnt(0)" ::: "memory")

__global__ __launch_bounds__(256) void init_ws(float* __restrict__ centsum,
                                               unsigned long long* __restrict__ gpacked,
                                               float* __restrict__ jsum) {
  int i = blockIdx.x * 256 + threadIdx.x;
  if (i < S_ROWS) centsum[i] = 0.f;
  if (i < B_ROWS) gpacked[i] = 0ull;
  if (i == 0) jsum[0] = 0.f;
}

// cbf_u = bf16(c), cbf_s = bf16(c * SCL); c = cent / max(||cent||, 1e-12)
__global__ __launch_bounds__(256) void normalize_centroids_bf16(const float* __restrict__ cent,
                                                                unsigned short* __restrict__ cbf_u,
                                                                unsigned short* __restrict__ cbf_s) {
  int row  = blockIdx.x * 4 + (threadIdx.x >> 6);
  int lane = threadIdx.x & 63;
  float2 v = ((const float2*)(cent + (size_t)row * DIM))[lane];
  float ss = v.x * v.x + v.y * v.y;
  #pragma unroll
  for (int m = 32; m; m >>= 1) ss += __shfl_xor(ss, m, 64);
  float inv = 1.0f / fmaxf(sqrtf(ss), 1e-12f);
  float cx = v.x * inv, cy = v.y * inv;
  ((unsigned int*)(cbf_u + (size_t)row * DIM))[lane] =
      (unsigned int)f2bf(cx) | ((unsigned int)f2bf(cy) << 16);
  ((unsigned int*)(cbf_s + (size_t)row * DIM))[lane] =
      (unsigned int)f2bf(cx * SCL) | ((unsigned int)f2bf(cy * SCL) << 16);
}

// issue one tile's 8 global_load_lds for this wave (rows [w*32, w*32+32))
__device__ __forceinline__ void stage_tile(const unsigned short* __restrict__ src, int base,
                                           int w, int lane, unsigned short* dst) {
  #pragma unroll
  for (int i = 0; i < 8; ++i) {
    int rb = w * 32 + i * 4;
    int r  = rb + (lane >> 4);
    int ch = (lane & 15) ^ (r & 7);
    gld16(src + (size_t)(base + r) * DIM + ch * 8, dst + rb * 128);
  }
}

// Strip GEMM body. Block = 128 rows x NT tiles of 128 cols, K=128 resident.
// 4 waves (64x64 each). A in registers; B double-buffered, counted-vmcnt pipeline:
// per tile: {ds_read 16 frags; lgkm(0); barrier; issue t+2 prefetch; MFMA; epilogue;
//            vmcnt(8); barrier}  -- vmcnt never drained to 0 in the loop.
// MODE 0: A=cbf_s rows, B=cbf_u; centsum[row] += sum_cols exp2(acc)
// MODE 1: A=features (f32->bf16), B=cbf_s; running max/argmax over cols
template <int MODE>
__device__ __forceinline__ void strip_body(int idx, const float* __restrict__ features,
                                           const unsigned short* __restrict__ cbf_u,
                                           const unsigned short* __restrict__ cbf_s,
                                           float* __restrict__ centsum,
                                           unsigned long long* __restrict__ gpacked,
                                           unsigned short* __restrict__ Bs0,
                                           unsigned short* __restrict__ Bs1) {
  constexpr int NT = (MODE == 0) ? 20 : 25;
  constexpr int CH = (MODE == 0) ? 5 : 4;
  const int chunk = idx % CH;
  const int row0  = (idx / CH) * 128;
  const int tile0 = chunk * NT;

  const unsigned short* Asrc = cbf_s;            // MODE 0 A operand (scaled)
  const unsigned short* Bsrc = (MODE == 0) ? cbf_u : cbf_s;

  const int t    = threadIdx.x;
  const int w    = t >> 6;
  const int lane = t & 63;
  const int wr = w >> 1, wc = w & 1;
  const int lg = lane >> 4, li = lane & 15;

  // ---- prologue: A tile into Bs0, then A fragments -> registers ----
  if (MODE == 0) {
    stage_tile(Asrc, row0, w, lane, Bs0);
    WAIT_VM0;
    __syncthreads();
  } else {
    #pragma unroll
    for (int i = 0; i < 8; ++i) {
      int q = i * 256 + t;
      int r = q >> 4, c = q & 15;
      const float* src = features + (size_t)(row0 + r) * DIM + c * 8;
      float4 v0 = *(const float4*)src;
      float4 v1 = *(const float4*)(src + 4);
      short8 h;
      h[0] = (short)f2bf(v0.x); h[1] = (short)f2bf(v0.y);
      h[2] = (short)f2bf(v0.z); h[3] = (short)f2bf(v0.w);
      h[4] = (short)f2bf(v1.x); h[5] = (short)f2bf(v1.y);
      h[6] = (short)f2bf(v1.z); h[7] = (short)f2bf(v1.w);
      *(short8*)&Bs0[r * 128 + (c ^ (r & 7)) * 8] = h;
    }
    __syncthreads();
  }

  short8 a[4][4];
  #pragma unroll
  for (int m = 0; m < 4; ++m)
    #pragma unroll
    for (int ks = 0; ks < 4; ++ks) {
      int r  = wr * 64 + m * 16 + li;
      int ch = (ks * 4 + lg) ^ (r & 7);
      a[m][ks] = *(const short8*)&Bs0[r * 128 + ch * 8];
    }
  __syncthreads();  // all A reads done before Bs0 is reused for B tiles

  // ---- running epilogue state ----
  float rs[4][4];
  float bv[4][4];
  int   bc[4][4];
  #pragma unroll
  for (int m = 0; m < 4; ++m)
    #pragma unroll
    for (int j = 0; j < 4; ++j) { rs[m][j] = 0.f; bv[m][j] = -3.0e38f; bc[m][j] = 0; }

  // ---- pre-stage tiles 0 and 1; wait tile 0 only (vmcnt 16 -> 8) ----
  stage_tile(Bsrc, tile0 * 128, w, lane, Bs0);
  stage_tile(Bsrc, (tile0 + 1) * 128, w, lane, Bs1);
  WAIT_VM8;
  __builtin_amdgcn_sched_barrier(0);
  __builtin_amdgcn_s_barrier();

  // ---- main loop ----
  for (int tt = 0; tt < NT; ++tt) {
    unsigned short* cur = (tt & 1) ? Bs1 : Bs0;

    // read all 16 B fragments of this tile
    short8 b[4][4];
    #pragma unroll
    for (int ks = 0; ks < 4; ++ks)
      #pragma unroll
      for (int n = 0; n < 4; ++n) {
        int c  = wc * 64 + n * 16 + li;
        int ch = (ks * 4 + lg) ^ (c & 7);
        b[ks][n] = *(const short8*)&cur[c * 128 + ch * 8];
      }
    WAIT_LGKM0;
    __builtin_amdgcn_sched_barrier(0);
    __builtin_amdgcn_s_barrier();            // all waves done reading `cur`

    if (tt + 2 < NT) {                       // prefetch t+2 into the buffer just freed
      stage_tile(Bsrc, (tile0 + tt + 2) * 128, w, lane, cur);
      __builtin_amdgcn_sched_barrier(0);
    }

    f32x4 acc[4][4];
    #pragma unroll
    for (int m = 0; m < 4; ++m)
      #pragma unroll
      for (int n = 0; n < 4; ++n) acc[m][n] = (f32x4){0.f, 0.f, 0.f, 0.f};

    __builtin_amdgcn_s_setprio(1);
    #pragma unroll
    for (int ks = 0; ks < 4; ++ks)
      #pragma unroll
      for (int m = 0; m < 4; ++m)
        #pragma unroll
        for (int n = 0; n < 4; ++n)
          acc[m][n] = __builtin_amdgcn_mfma_f32_16x16x32_bf16(a[m][ks], b[ks][n], acc[m][n], 0, 0, 0);
    __builtin_amdgcn_s_setprio(0);

    // per-tile running epilogue (C/D: col = li, row = lg*4 + j)
    if (MODE == 0) {
      #pragma unroll
      for (int m = 0; m < 4; ++m)
        #pragma unroll
        for (int n = 0; n < 4; ++n)
          #pragma unroll
          for (int j = 0; j < 4; ++j)
            rs[m][j] += exp2f(acc[m][n][j]);
    } else {
      const int cbase = (tile0 + tt) * 128 + wc * 64 + li;
      #pragma unroll
      for (int m = 0; m < 4; ++m)
        #pragma unroll
        for (int j = 0; j < 4; ++j)
          #pragma unroll
          for (int n = 0; n < 4; ++n) {
            float v = acc[m][n][j];
            if (v > bv[m][j]) { bv[m][j] = v; bc[m][j] = cbase + n * 16; }  // strict >: smallest col wins
          }
    }

    if (tt + 1 < NT) {
      if (tt + 2 < NT) { WAIT_VM8; } else { WAIT_VM0; }   // tile t+1's loads landed
      __builtin_amdgcn_sched_barrier(0);
      __builtin_amdgcn_s_barrier();
    }
  }

  // ---- strip-end reduction + one atomic per row ----
  if (MODE == 0) {
    #pragma unroll
    for (int m = 0; m < 4; ++m)
      #pragma unroll
      for (int j = 0; j < 4; ++j) {
        float s = rs[m][j];
        #pragma unroll
        for (int msk = 1; msk < 16; msk <<= 1) s += __shfl_xor(s, msk, 64);
        if (li == 0) atomicAdd(&centsum[row0 + wr * 64 + m * 16 + lg * 4 + j], s);
      }
  } else {
    #pragma unroll
    for (int m = 0; m < 4; ++m)
      #pragma unroll
      for (int j = 0; j < 4; ++j) {
        float v = bv[m][j];
        int   c = bc[m][j];
        #pragma unroll
        for (int msk = 1; msk < 16; msk <<= 1) {
          float ov = __shfl_xor(v, msk, 64);
          int   oc = __shfl_xor(c, msk, 64);
          if (ov > v || (ov == v && oc < c)) { v = ov; c = oc; }
        }
        if (li == 0) atomicMax(&gpacked[row0 + wr * 64 + m * 16 + lg * 4 + j], packMax(v, c));
      }
  }
}

// Fused dispatch: blocks 0..999 alternate MODE0/MODE1; 1000..1011 are MODE1 tail.
__global__ __launch_bounds__(256, 2) void fused_strips(const float* __restrict__ features,
                                                       const unsigned short* __restrict__ cbf_u,
                                                       const unsigned short* __restrict__ cbf_s,
                                                       float* __restrict__ centsum,
                                                       unsigned long long* __restrict__ gpacked) {
  __shared__ unsigned short Bs[2][128 * 128];  // 64 KB
  int bid = blockIdx.x;
  if (bid < 1000) {
    if ((bid & 1) == 0)
      strip_body<0>(bid >> 1, features, cbf_u, cbf_s, centsum, gpacked, Bs[0], Bs[1]);
    else
      strip_body<1>(bid >> 1, features, cbf_u, cbf_s, centsum, gpacked, Bs[0], Bs[1]);
  } else {
    strip_body<1>(500 + (bid - 1000), features, cbf_u, cbf_s, centsum, gpacked, Bs[0], Bs[1]);
  }
}

__global__ __launch_bounds__(256) void finalize_rows(const unsigned long long* __restrict__ gpacked,
                                                     const float* __restrict__ centsum,
                                                     float* __restrict__ jsum) {
  __shared__ float sdata[4];
  int b = blockIdx.x * 256 + threadIdx.x;
  unsigned long long pk = gpacked[b];
  unsigned int key = (unsigned int)(pk >> 32);
  unsigned int col = 0xFFFFFFFFu - (unsigned int)(pk & 0xFFFFFFFFu);
  unsigned int bits = (key & 0x80000000u) ? (key & 0x7FFFFFFFu) : ~key;
  float msc = __uint_as_float(bits);       // max dot * log2(e)/T
  float p = exp2f(msc);                    // = exp(max dot / T)
  float J = logf(p) - logf(p + centsum[col]);  // BALANCE = 1.0
  #pragma unroll
  for (int msk = 1; msk < 64; msk <<= 1) J += __shfl_xor(J, msk, 64);
  int lane = threadIdx.x & 63, wv = threadIdx.x >> 6;
  if (lane == 0) sdata[wv] = J;
  __syncthreads();
  if (threadIdx.x == 0) atomicAdd(jsum, sdata[0] + sdata[1] + sdata[2] + sdata[3]);
}

__global__ void write_out(const float* __restrict__ jsum, float* __restrict__ out) {
  out[0] = -(jsum[0] / (float)B_ROWS);
}

extern "C" void kernel_launch(void* const* d_in, const int* in_sizes, int n_in,
                              void* d_out, int out_size, void* d_ws, size_t ws_size,
                              hipStream_t stream) {
  const float* features  = (const float*)d_in[0];
  const float* centroids = (const float*)d_in[1];
  float* out = (float*)d_out;

  // ws: cbf_u[S*D] u16 | cbf_s[S*D] u16 | centsum[S] f32 | gpacked[B] u64 | jsum f32 (~6.74 MB)
  unsigned short* cbf_u = (unsigned short*)d_ws;
  unsigned short* cbf_s = cbf_u + (size_t)S_ROWS * DIM;
  float* centsum = (float*)(cbf_s + (size_t)S_ROWS * DIM);
  unsigned long long* gpacked = (unsigned long long*)(centsum + S_ROWS);
  float* jsum = (float*)(gpacked + B_ROWS);

  init_ws<<<dim3(64), dim3(256), 0, stream>>>(centsum, gpacked, jsum);
  normalize_centroids_bf16<<<dim3(S_ROWS / 4), dim3(256), 0, stream>>>(centroids, cbf_u, cbf_s);
  fused_strips<<<dim3(1012), dim3(256), 0, stream>>>(features, cbf_u, cbf_s, centsum, gpacked);
  finalize_rows<<<dim3(B_ROWS / 256), dim3(256), 0, stream>>>(gpacked, centsum, jsum);
  write_out<<<dim3(1), dim3(1), 0, stream>>>(jsum, out);
}